// Round 7
// baseline (385.508 us; speedup 1.0000x reference)
//
#include <hip/hip_runtime.h>

// LSTM B=1024,T=512,F=40,H=50. History: r7=267us (2-phase, sh_g exchange,
// transc dense on 2 waves). r9/r12 proved transc-per-wave is first-order ->
// keep r7's dense pointwise. r11 proved more blocks/CU hurts. r13 shortens
// r7's serial chain: the x-projection GEMM has no h-dependency, so it is
// computed in PHASE 2 of the previous step (overlapping the pointwise,
// MFMA pipe || transc pipe) into register dp[], staged from a separate
// double-buffered x-panel. Phase 1 becomes dp + 2 dependent h-MFMAs
// (was 3) with 2 panel ds_reads (was 3).
//
// Panels: hP[2][16][72] (h cols 0..49), xP[2][16][72] (x cols 0..39),
// stride 72 shorts = 36 banks -> 2-way conflict on b128 reads (free).
// x_s lives in xP[s&1]: staged at step s-2 phase2, read at s-1 phase2,
// barriers separate all hazards. dp handoff is register-private.
// GEMM mapping identical to r7: A=weights rows'=4u+g interleaved, 13
// M-tiles split 3/3/3/4 over 4 waves; D lane (m16,q) = gates r of unit
// 4*tile+q, batch col m16 (m16<2 real). Pointwise on 100 dense lanes
// (waves 0-1), x stagers wave 2, raw lgkmcnt-only barriers.

constexpr int kT   = 512;
constexpr int kF   = 40;
constexpr int kH   = 50;
constexpr int kMB  = 2;      // real batches per block
constexpr int kPR  = 72;     // panel row stride in shorts (144 B = 36 banks)
constexpr int kGRow = 208;   // sh_g row stride in dwords (13 tiles * 16)

typedef __attribute__((ext_vector_type(8))) short bf16x8;
typedef __attribute__((ext_vector_type(4))) float f32x4;

__device__ __forceinline__ unsigned short f2bf(float f) {
    union { float f; unsigned u; } v; v.f = f;
    return (unsigned short)((v.u + 0x7FFFu + ((v.u >> 16) & 1u)) >> 16);
}
__device__ __forceinline__ float fast_sigmoid(float v) {
    return __builtin_amdgcn_rcpf(1.f + __expf(-v));
}
__device__ __forceinline__ float fast_tanh(float v) {
    return 1.f - 2.f * __builtin_amdgcn_rcpf(__expf(2.f * v) + 1.f);
}

__global__ __launch_bounds__(256, 2)
void lstm_mfma_pipe(
    const float* __restrict__ x,      // [B,T,F]
    const float* __restrict__ W_ih,   // [4H,F]
    const float* __restrict__ W_hh,   // [4H,H]
    const float* __restrict__ b_ih,   // [4H]
    const float* __restrict__ b_hh,   // [4H]
    const float* __restrict__ W1,     // [10,H]
    const float* __restrict__ b1,     // [10]
    const float* __restrict__ W2,     // [1,10]
    const float* __restrict__ b2,     // [1]
    float* __restrict__ out)          // [B]
{
    const int tid  = threadIdx.x;
    const int lane = tid & 63;
    const int wave = tid >> 6;
    const int bb   = blockIdx.x;
    const int m16  = lane & 15;    // D col = batch
    const int q    = lane >> 4;    // quad

    __shared__ short shP[4][16][kPR];   // [0..1]=h dbuf, [2..3]=x dbuf
    __shared__ float sh_g[kMB][kGRow];  // gate pre-acts, rows' = 4u+r
    __shared__ float sh_hf[kMB][kH + 2];
    __shared__ float sh_head[kMB][10];

    const int t0 = (wave == 3) ? 9 : wave * 3;   // first tile of this wave
    const int NT = (wave == 3) ? 4 : 3;          // tiles 3/3/3/4 = 13

    // zero all panels (pads + batch rows 2..15 stay 0 forever)
    { int* z = (int*)shP; for (int i = tid; i < 2304; i += 256) z[i] = 0; }

    // ---- A-frag weights: chunks 0,1 = W_hh (h k), chunks 2,3 = W_ih (x) --
    bf16x8 wa[4][4];
    f32x4  bias4[4];
    const int uA = m16 >> 2, gA = m16 & 3;
#pragma unroll
    for (int i = 0; i < 4; ++i) {
        const int tl = t0 + i;
        const int unitA = 4 * tl + uA;
        const bool live = (i < NT) && (unitA < kH);
        const int orow = live ? (unitA + 50 * gA) : 0;
#pragma unroll
        for (int c = 0; c < 4; ++c) {
            bf16x8 v;
#pragma unroll
            for (int j = 0; j < 8; ++j) {
                float wv = 0.f;
                if (live) {
                    if (c < 2) {
                        const int k = 32 * c + q * 8 + j;
                        if (k < kH) wv = W_hh[orow * kH + k];
                    } else {
                        const int xc = 32 * (c - 2) + q * 8 + j;
                        if (xc < kF) wv = W_ih[orow * kF + xc];
                    }
                }
                v[j] = (short)f2bf(wv);
            }
            wa[i][c] = v;
        }
        const int uD = 4 * tl + q;
#pragma unroll
        for (int r = 0; r < 4; ++r)
            bias4[i][r] = (i < NT && uD < kH)
                        ? (b_ih[uD + 50 * r] + b_hh[uD + 50 * r]) : 0.f;
    }

    // ---- dense pointwise owners: tid<100 -> (batch pm, unit pu) ----
    const bool pw = (tid < kMB * kH);
    const int  pm = pw ? (tid / kH) : 0;
    const int  pu = pw ? (tid % kH) : 0;
    float c     = (pw && pu == 0) ? 1.f : 0.f;   // c0[:,0] = 1
    float lasth = 0.f;

    // ---- x stagers: wave 2 lanes 0..39 own (batch xm, float2 chunk xd) ----
    const bool xs = (tid >= 128 && tid < 128 + kMB * 20);
    const int  xi = xs ? (tid - 128) : 0;
    const int  xm = xi / 20, xd = xi % 20;
    const float* xrow = x + ((size_t)(bb * kMB + xm) * kT) * kF + 2 * xd;

    float2 pa = {0.f, 0.f}, pb = {0.f, 0.f};
    __syncthreads();                              // zero-init done
    if (xs) {
        float2 v0 = *(const float2*)xrow;               // x_0 -> xP[0]
        unsigned p0 = (unsigned)f2bf(v0.x) | ((unsigned)f2bf(v0.y) << 16);
        *(unsigned*)&shP[2][xm][2 * xd] = p0;
        float2 v1 = *(const float2*)(xrow + (size_t)1 * kF);  // x_1 -> xP[1]
        unsigned p1 = (unsigned)f2bf(v1.x) | ((unsigned)f2bf(v1.y) << 16);
        *(unsigned*)&shP[3][xm][2 * xd] = p1;
        pa = *(const float2*)(xrow + (size_t)2 * kF);   // x_2 (staged t=0)
        pb = *(const float2*)(xrow + (size_t)3 * kF);   // x_3 (staged t=1)
    }
    __syncthreads();                              // x_0, x_1 staged

    // ---- prologue: dp for t=0 from xP[0] ----
    f32x4 dp[4];
    {
        const short* xp = &shP[2][m16][0];
        bf16x8 xv0 = *(const bf16x8*)(xp + q * 8);
        bf16x8 xv1 = *(const bf16x8*)(xp + 32 + q * 8);
#pragma unroll
        for (int i = 0; i < 4; ++i) {
            if (i < NT) {
                f32x4 d = bias4[i];
                d = __builtin_amdgcn_mfma_f32_16x16x32_bf16(wa[i][2], xv0, d, 0, 0, 0);
                d = __builtin_amdgcn_mfma_f32_16x16x32_bf16(wa[i][3], xv1, d, 0, 0, 0);
                dp[i] = d;
            }
        }
    }

    // ---- one step; CUR = t&1 compile-time via 2-phase unroll ----
    auto step = [&](int t, int CUR, float2& pf) {
        // phase 1: h-GEMM only (x-part carried in dp from last phase 2)
        const short* hp = &shP[CUR][m16][0];
        bf16x8 h0 = *(const bf16x8*)(hp + q * 8);        // h k  0..31
        bf16x8 h1 = *(const bf16x8*)(hp + 32 + q * 8);   // h k 32..63
#pragma unroll
        for (int i = 0; i < 4; ++i) {
            if (i < NT) {                                // wave-uniform
                f32x4 d = dp[i];
                d = __builtin_amdgcn_mfma_f32_16x16x32_bf16(wa[i][0], h0, d, 0, 0, 0);
                d = __builtin_amdgcn_mfma_f32_16x16x32_bf16(wa[i][1], h1, d, 0, 0, 0);
                if (m16 < kMB)                           // 2 real cols only
                    *(f32x4*)&sh_g[m16][16 * (t0 + i) + 4 * q] = d;
            }
        }
        // barrier A: sh_g ready (LDS-only drain; x prefetch stays in flight)
        asm volatile("s_waitcnt lgkmcnt(0)\n\ts_barrier" ::: "memory");

        // phase 2: pointwise (waves 0-1) || x-stage (wave 2) || x-GEMM (all)
        if (pw) {
            f32x4 g = *(const f32x4*)&sh_g[pm][4 * pu];  // i,f,g,o of unit pu
            float i_s = fast_sigmoid(g[0]);
            float f_s = fast_sigmoid(g[1]);
            float g_t = fast_tanh   (g[2]);
            float o_s = fast_sigmoid(g[3]);
            c = fmaf(f_s, c, i_s * g_t);
            lasth = o_s * fast_tanh(c);
            if (t + 1 < kT)
                shP[CUR ^ 1][pm][pu] = (short)f2bf(lasth);   // h panel t+1
        } else if (xs) {
            if (t + 2 < kT) {                            // stage x_{t+2}
                unsigned pk = (unsigned)f2bf(pf.x) | ((unsigned)f2bf(pf.y) << 16);
                *(unsigned*)&shP[2 + CUR][xm][2 * xd] = pk;
            }
            if (t + 4 < kT)                              // prefetch x_{t+4}
                pf = *(const float2*)(xrow + (size_t)(t + 4) * kF);
        }
        if (t + 1 < kT) {                                // dp for step t+1
            const short* xp = &shP[2 + (CUR ^ 1)][m16][0];   // x_{t+1}
            bf16x8 xv0 = *(const bf16x8*)(xp + q * 8);
            bf16x8 xv1 = *(const bf16x8*)(xp + 32 + q * 8);
#pragma unroll
            for (int i = 0; i < 4; ++i) {
                if (i < NT) {
                    f32x4 d = bias4[i];
                    d = __builtin_amdgcn_mfma_f32_16x16x32_bf16(wa[i][2], xv0, d, 0, 0, 0);
                    d = __builtin_amdgcn_mfma_f32_16x16x32_bf16(wa[i][3], xv1, d, 0, 0, 0);
                    dp[i] = d;
                }
            }
        }
        // barrier B: h panel + dp ready for next step
        asm volatile("s_waitcnt lgkmcnt(0)\n\ts_barrier" ::: "memory");
    };

    for (int t = 0; t < kT; t += 2) {
        step(t,     0, pa);
        step(t + 1, 1, pb);
    }

    // ---- head: relu(h @ W1.T + b1) @ W2.T + b2 + x[b, T-1, 0] ----
    if (pw) sh_hf[pm][pu] = lasth;
    __syncthreads();
    if (tid < kMB * 10) {
        const int m = tid / 10, j = tid % 10;
        float acc = b1[j];
#pragma unroll
        for (int k = 0; k < kH; ++k) acc = fmaf(sh_hf[m][k], W1[j * kH + k], acc);
        sh_head[m][j] = fmaxf(acc, 0.f);
    }
    __syncthreads();
    if (tid < kMB) {
        float acc = b2[0];
#pragma unroll
        for (int j2 = 0; j2 < 10; ++j2) acc = fmaf(sh_head[tid][j2], W2[j2], acc);
        const int bidx = bb * kMB + tid;
        out[bidx] = acc + x[((size_t)bidx * kT + (kT - 1)) * kF];
    }
}

extern "C" void kernel_launch(void* const* d_in, const int* in_sizes, int n_in,
                              void* d_out, int out_size, void* d_ws, size_t ws_size,
                              hipStream_t stream) {
    const float* x    = (const float*)d_in[0];
    const float* W_ih = (const float*)d_in[1];
    const float* W_hh = (const float*)d_in[2];
    const float* b_ih = (const float*)d_in[3];
    const float* b_hh = (const float*)d_in[4];
    const float* W1   = (const float*)d_in[5];
    const float* b1   = (const float*)d_in[6];
    const float* W2   = (const float*)d_in[7];
    const float* b2   = (const float*)d_in[8];
    float* out = (float*)d_out;

    lstm_mfma_pipe<<<dim3(1024 / kMB), dim3(256), 0, stream>>>(
        x, W_ih, W_hh, b_ih, b_hh, W1, b1, W2, b2, out);
}

// Round 9
// 364.775 us; speedup vs baseline: 1.0568x; 1.0568x over previous
//
#include <hip/hip_runtime.h>

// LSTM B=1024,T=512,F=40,H=50. r7=267us is the structural optimum found:
// 2-phase step, sh_g exchange, transc dense on waves 0-1, 2 blocks/CU.
// Failed variants: r8 wave-local/1-barrier (280), r9 in-place transc (440),
// r11 4 blocks/CU (372), r12 swapped-D (293), r13 x-GEMM hoist (301).
// Lessons: transc instrs/wave is first-order; segment removal that adds
// issue to critical waves loses; conflicts are the PANEL b128 reads
// (r9 proved sh_g's share is ~0): stride 52 dwords -> 52m%32 spans only
// 8 banks -> 8-way conflict each dword-phase.
// r14 = r7 + two micro-fixes (resubmit: r8 bench = infra failure 2x, kernel
// audited clean -- zero-count, alignment, bounds, barrier uniformity):
//  (1) panel row stride 50 dwords (100 shorts) + 2x ds_read_b64 per chunk:
//      50m%32 spans 16 banks -> ~4-way. Rows stay 8B-aligned (200B).
//  (2) s_setprio(1) around the phase-2 pointwise on waves 0-1 (wave-uniform)
//      so the critical transc wave wins CU arbitration vs the other block's
//      GEMM waves.
// Everything else byte-identical to r7 (incl. raw lgkmcnt-only barriers).

constexpr int kT   = 512;
constexpr int kF   = 40;
constexpr int kH   = 50;
constexpr int kMB  = 2;      // real batches per block
constexpr int kRowS = 100;   // panel row stride in shorts (200 B, 50 dwords)
constexpr int kGRow = 208;   // sh_g row stride in dwords (13 tiles * 16)

typedef __attribute__((ext_vector_type(8))) short bf16x8;
typedef __attribute__((ext_vector_type(4))) short bf16x4;
typedef __attribute__((ext_vector_type(4))) float f32x4;

__device__ __forceinline__ unsigned short f2bf(float f) {
    union { float f; unsigned u; } v; v.f = f;
    return (unsigned short)((v.u + 0x7FFFu + ((v.u >> 16) & 1u)) >> 16);
}
__device__ __forceinline__ float fast_sigmoid(float v) {
    return __builtin_amdgcn_rcpf(1.f + __expf(-v));
}
__device__ __forceinline__ float fast_tanh(float v) {
    return 1.f - 2.f * __builtin_amdgcn_rcpf(__expf(2.f * v) + 1.f);
}

__global__ __launch_bounds__(256, 2)
void lstm_mfma_nb(
    const float* __restrict__ x,      // [B,T,F]
    const float* __restrict__ W_ih,   // [4H,F]
    const float* __restrict__ W_hh,   // [4H,H]
    const float* __restrict__ b_ih,   // [4H]
    const float* __restrict__ b_hh,   // [4H]
    const float* __restrict__ W1,     // [10,H]
    const float* __restrict__ b1,     // [10]
    const float* __restrict__ W2,     // [1,10]
    const float* __restrict__ b2,     // [1]
    float* __restrict__ out)          // [B]
{
    const int tid  = threadIdx.x;
    const int lane = tid & 63;
    const int wave = tid >> 6;
    const int bb   = blockIdx.x;
    const int m16  = lane & 15;    // D col = batch
    const int q    = lane >> 4;    // quad

    __shared__ short sh_comb[2][16][kRowS];  // [x(0..39)|h(40..89)|pad] bf16
    __shared__ float sh_g[kMB][kGRow];       // gate pre-acts, rows' = 4u+r
    __shared__ float sh_hf[kMB][kH + 2];     // final h fp32
    __shared__ float sh_head[kMB][10];

    const int t0 = (wave == 3) ? 9 : wave * 3;   // first tile of this wave
    const int NT = (wave == 3) ? 4 : 3;          // tiles 3/3/3/4 = 13

    // zero the combined panels (pads + batch cols 2..15 stay 0 forever)
    { int* z = (int*)sh_comb; for (int i = tid; i < 1600; i += 256) z[i] = 0; }

    // ---- A-frag weights (registers) + bias for C operand ----
    bf16x8 wa[4][3];
    float  bias[4][4];
    const int uA = m16 >> 2, gA = m16 & 3;
#pragma unroll
    for (int i = 0; i < 4; ++i) {
        const int tl = t0 + i;
        const int unitA = 4 * tl + uA;
        const bool live = (i < NT) && (unitA < kH);
        const int orow = live ? (unitA + 50 * gA) : 0;
#pragma unroll
        for (int kk = 0; kk < 3; ++kk) {
            bf16x8 v;
#pragma unroll
            for (int j = 0; j < 8; ++j) {
                const int k = kk * 32 + q * 8 + j;
                float wv = 0.f;
                if (live) {
                    if (k < kF)           wv = W_ih[orow * kF + k];
                    else if (k < kF + kH) wv = W_hh[orow * kH + (k - kF)];
                }
                v[j] = (short)f2bf(wv);
            }
            wa[i][kk] = v;
        }
        const int uD = 4 * tl + q;
#pragma unroll
        for (int r = 0; r < 4; ++r)
            bias[i][r] = (i < NT && uD < kH)
                       ? (b_ih[uD + 50 * r] + b_hh[uD + 50 * r]) : 0.f;
    }

    // ---- dense pointwise owners: tid<100 -> (batch pm, unit pu) ----
    const bool pw = (tid < kMB * kH);
    const int  pm = pw ? (tid / kH) : 0;
    const int  pu = pw ? (tid % kH) : 0;
    float c     = (pw && pu == 0) ? 1.f : 0.f;   // c0[:,0] = 1
    float lasth = 0.f;

    // ---- x stagers: wave 2 lanes 0..39 own (batch xm, float2 chunk xd) ----
    const bool xs = (tid >= 128 && tid < 128 + kMB * 20);
    const int  xi = xs ? (tid - 128) : 0;
    const int  xm = xi / 20, xd = xi % 20;
    const float* xrow = x + ((size_t)(bb * kMB + xm) * kT) * kF + 2 * xd;

    float2 pa = {0.f, 0.f}, pb = {0.f, 0.f};
    __syncthreads();                              // zero-init done
    if (xs) {
        float2 v0 = *(const float2*)xrow;         // x_0
        unsigned pk = (unsigned)f2bf(v0.x) | ((unsigned)f2bf(v0.y) << 16);
        *(unsigned*)&sh_comb[0][xm][2 * xd] = pk;
        pa = *(const float2*)(xrow + (size_t)1 * kF);   // x_1 (used t=0)
        pb = *(const float2*)(xrow + (size_t)2 * kF);   // x_2 (used t=1)
    }
    __syncthreads();

    // ---- one step; CUR = t&1 compile-time via 2-phase unroll ----
    auto step = [&](int t, int CUR, float2& pf) {
        const short* rowp = &sh_comb[CUR][m16][0];
        // 2x b64 per 32-k chunk: stride-50-dword rows -> ~4-way banks (was 8)
        bf16x8 bv0, bv1, bv2;
        {
            bf16x4 a0 = *(const bf16x4*)(rowp +      q * 8);
            bf16x4 a1 = *(const bf16x4*)(rowp +      q * 8 + 4);
            bf16x4 b0 = *(const bf16x4*)(rowp + 32 + q * 8);
            bf16x4 b1 = *(const bf16x4*)(rowp + 32 + q * 8 + 4);
            bf16x4 c0v = *(const bf16x4*)(rowp + 64 + q * 8);
            bf16x4 c1v = *(const bf16x4*)(rowp + 64 + q * 8 + 4);
#pragma unroll
            for (int j = 0; j < 4; ++j) {
                bv0[j] = a0[j]; bv0[4 + j] = a1[j];
                bv1[j] = b0[j]; bv1[4 + j] = b1[j];
                bv2[j] = c0v[j]; bv2[4 + j] = c1v[j];
            }
        }
#pragma unroll
        for (int i = 0; i < 4; ++i) {
            if (i < NT) {                                   // wave-uniform
                f32x4 d;
                d[0] = bias[i][0]; d[1] = bias[i][1];
                d[2] = bias[i][2]; d[3] = bias[i][3];
                d = __builtin_amdgcn_mfma_f32_16x16x32_bf16(wa[i][0], bv0, d, 0, 0, 0);
                d = __builtin_amdgcn_mfma_f32_16x16x32_bf16(wa[i][1], bv1, d, 0, 0, 0);
                d = __builtin_amdgcn_mfma_f32_16x16x32_bf16(wa[i][2], bv2, d, 0, 0, 0);
                if (m16 < kMB)                              // 2 real cols only
                    *(f32x4*)&sh_g[m16][16 * (t0 + i) + 4 * q] = d;
            }
        }
        // barrier A: sh_g ready. LDS-only drain; x prefetch stays in flight.
        asm volatile("s_waitcnt lgkmcnt(0)\n\ts_barrier" ::: "memory");

        short* nbuf = &sh_comb[CUR ^ 1][0][0];
        if (wave < 2) __builtin_amdgcn_s_setprio(1);        // critical waves
        if (pw) {
            f32x4 g = *(const f32x4*)&sh_g[pm][4 * pu];     // i,f,g,o of unit pu
            float i_s = fast_sigmoid(g[0]);
            float f_s = fast_sigmoid(g[1]);
            float g_t = fast_tanh   (g[2]);
            float o_s = fast_sigmoid(g[3]);
            c = fmaf(f_s, c, i_s * g_t);
            lasth = o_s * fast_tanh(c);
            if (t + 1 < kT)
                nbuf[pm * kRowS + kF + pu] = (short)f2bf(lasth);
        } else if (xs) {
            if (t + 1 < kT) {
                unsigned pk = (unsigned)f2bf(pf.x) | ((unsigned)f2bf(pf.y) << 16);
                *(unsigned*)&nbuf[xm * kRowS + 2 * xd] = pk;
            }
            if (t + 3 < kT)                                  // distance-2 prefetch
                pf = *(const float2*)(xrow + (size_t)(t + 3) * kF);
        }
        if (wave < 2) __builtin_amdgcn_s_setprio(0);
        // barrier B: next panel ready.
        asm volatile("s_waitcnt lgkmcnt(0)\n\ts_barrier" ::: "memory");
    };

    for (int t = 0; t < kT; t += 2) {
        step(t,     0, pa);
        step(t + 1, 1, pb);
    }

    // ---- head: relu(h @ W1.T + b1) @ W2.T + b2 + x[b, T-1, 0] ----
    if (pw) sh_hf[pm][pu] = lasth;
    __syncthreads();
    if (tid < kMB * 10) {
        const int m = tid / 10, j = tid % 10;
        float acc = b1[j];
#pragma unroll
        for (int k = 0; k < kH; ++k) acc = fmaf(sh_hf[m][k], W1[j * kH + k], acc);
        sh_head[m][j] = fmaxf(acc, 0.f);
    }
    __syncthreads();
    if (tid < kMB) {
        float acc = b2[0];
#pragma unroll
        for (int j2 = 0; j2 < 10; ++j2) acc = fmaf(sh_head[tid][j2], W2[j2], acc);
        const int bidx = bb * kMB + tid;
        out[bidx] = acc + x[((size_t)bidx * kT + (kT - 1)) * kF];
    }
}

extern "C" void kernel_launch(void* const* d_in, const int* in_sizes, int n_in,
                              void* d_out, int out_size, void* d_ws, size_t ws_size,
                              hipStream_t stream) {
    const float* x    = (const float*)d_in[0];
    const float* W_ih = (const float*)d_in[1];
    const float* W_hh = (const float*)d_in[2];
    const float* b_ih = (const float*)d_in[3];
    const float* b_hh = (const float*)d_in[4];
    const float* W1   = (const float*)d_in[5];
    const float* b1   = (const float*)d_in[6];
    const float* W2   = (const float*)d_in[7];
    const float* b2   = (const float*)d_in[8];
    float* out = (float*)d_out;

    lstm_mfma_nb<<<dim3(1024 / kMB), dim3(256), 0, stream>>>(
        x, W_ih, W_hh, b_ih, b_hh, W1, b1, W2, b2, out);
}

// Round 10
// 359.902 us; speedup vs baseline: 1.0711x; 1.0135x over previous
//
#include <hip/hip_runtime.h>

// LSTM B=1024,T=512,F=40,H=50. r7=267us dispatch is the structural optimum:
// 2-phase step, sh_g exchange, transc dense on waves 0-1, kMB=2, 2 blocks/CU.
// Attacked and closed: r8 1-barrier (280), r9 in-place transc (440), r10
// lgkmcnt-only barriers (neutral), r11 4 blocks/CU (372), r12 swapped-D
// (293), r13 x-GEMM hoist (301), r14 conflict-free panel+setprio (288;
// conflicts 1.34e7->1.05e6 = 13x yet SLOWER -> conflicts NOT on the chain).
// Remaining gap: ~1250cy/step vs ~650cy single-chain critical path, all
// pipes <26%. The 2 co-resident chains launch IN-PHASE and stay there
// (in-phase is a neutral equilibrium: contention slows both equally), so
// A's MFMA phase never fills B's barrier bubble.
// r15 = r7 + ONE change: half-step s_sleep(10) (~640cy) offset for one
// block of each co-resident pair -> anti-phase interleave; phase 1
// (MFMA/ds_read) of one chain overlaps phase 2 (transc) of the other.
// Pair-parity key (bb ^ bb>>8)&1 covers both plausible block->CU mappings
// (consecutive pairs 2b/2b+1 and stride-256 round-robin b/b+256).
//
// GEMM per step: G^T[208,16] = W'[208,96] @ [x|h]^T[96,16], rows' =
// 4*unit+gate (i,f,g,o interleaved), 13 M-tiles split 3/3/3/4 over 4 waves,
// 3 K-chunks (K=96: x 0..39 | h 40..89 | pad). D lane (m16,q) holds gates
// r=0..3 of unit 4*tile+q, batch col m16 (only m16<2 real). Pointwise on
// 100 dense lanes (waves 0-1), x stagers wave 2, distance-2 prefetch.

constexpr int kT   = 512;
constexpr int kF   = 40;
constexpr int kH   = 50;
constexpr int kMB  = 2;      // real batches per block
constexpr int kRowS = 104;   // combined panel row stride in shorts (208 B)
constexpr int kGRow = 208;   // sh_g row stride in dwords (13 tiles * 16)

typedef __attribute__((ext_vector_type(8))) short bf16x8;
typedef __attribute__((ext_vector_type(4))) float f32x4;

__device__ __forceinline__ unsigned short f2bf(float f) {
    union { float f; unsigned u; } v; v.f = f;
    return (unsigned short)((v.u + 0x7FFFu + ((v.u >> 16) & 1u)) >> 16);
}
__device__ __forceinline__ float fast_sigmoid(float v) {
    return __builtin_amdgcn_rcpf(1.f + __expf(-v));
}
__device__ __forceinline__ float fast_tanh(float v) {
    return 1.f - 2.f * __builtin_amdgcn_rcpf(__expf(2.f * v) + 1.f);
}

__global__ __launch_bounds__(256, 2)
void lstm_mfma_offset(
    const float* __restrict__ x,      // [B,T,F]
    const float* __restrict__ W_ih,   // [4H,F]
    const float* __restrict__ W_hh,   // [4H,H]
    const float* __restrict__ b_ih,   // [4H]
    const float* __restrict__ b_hh,   // [4H]
    const float* __restrict__ W1,     // [10,H]
    const float* __restrict__ b1,     // [10]
    const float* __restrict__ W2,     // [1,10]
    const float* __restrict__ b2,     // [1]
    float* __restrict__ out)          // [B]
{
    const int tid  = threadIdx.x;
    const int lane = tid & 63;
    const int wave = tid >> 6;
    const int bb   = blockIdx.x;
    const int m16  = lane & 15;    // D col = batch
    const int q    = lane >> 4;    // quad

    __shared__ short sh_comb[2][16][kRowS];  // [x(0..39)|h(40..89)|pad] bf16
    __shared__ float sh_g[kMB][kGRow];       // gate pre-acts, rows' = 4u+r
    __shared__ float sh_hf[kMB][kH + 2];     // final h fp32
    __shared__ float sh_head[kMB][10];

    const int t0 = (wave == 3) ? 9 : wave * 3;   // first tile of this wave
    const int NT = (wave == 3) ? 4 : 3;          // tiles 3/3/3/4 = 13

    // zero the combined panels (pads + batch cols 2..15 stay 0 forever)
    { int* z = (int*)sh_comb; for (int i = tid; i < 1664; i += 256) z[i] = 0; }

    // ---- A-frag weights (registers) + bias for C operand ----
    bf16x8 wa[4][3];
    float  bias[4][4];
    const int uA = m16 >> 2, gA = m16 & 3;
#pragma unroll
    for (int i = 0; i < 4; ++i) {
        const int tl = t0 + i;
        const int unitA = 4 * tl + uA;
        const bool live = (i < NT) && (unitA < kH);
        const int orow = live ? (unitA + 50 * gA) : 0;
#pragma unroll
        for (int kk = 0; kk < 3; ++kk) {
            bf16x8 v;
#pragma unroll
            for (int j = 0; j < 8; ++j) {
                const int k = kk * 32 + q * 8 + j;
                float wv = 0.f;
                if (live) {
                    if (k < kF)           wv = W_ih[orow * kF + k];
                    else if (k < kF + kH) wv = W_hh[orow * kH + (k - kF)];
                }
                v[j] = (short)f2bf(wv);
            }
            wa[i][kk] = v;
        }
        const int uD = 4 * tl + q;
#pragma unroll
        for (int r = 0; r < 4; ++r)
            bias[i][r] = (i < NT && uD < kH)
                       ? (b_ih[uD + 50 * r] + b_hh[uD + 50 * r]) : 0.f;
    }

    // ---- dense pointwise owners: tid<100 -> (batch pm, unit pu) ----
    const bool pw = (tid < kMB * kH);
    const int  pm = pw ? (tid / kH) : 0;
    const int  pu = pw ? (tid % kH) : 0;
    float c     = (pw && pu == 0) ? 1.f : 0.f;   // c0[:,0] = 1
    float lasth = 0.f;

    // ---- x stagers: wave 2 lanes 0..39 own (batch xm, float2 chunk xd) ----
    const bool xs = (tid >= 128 && tid < 128 + kMB * 20);
    const int  xi = xs ? (tid - 128) : 0;
    const int  xm = xi / 20, xd = xi % 20;
    const float* xrow = x + ((size_t)(bb * kMB + xm) * kT) * kF + 2 * xd;

    float2 pa = {0.f, 0.f}, pb = {0.f, 0.f};
    __syncthreads();                              // zero-init done
    if (xs) {
        float2 v0 = *(const float2*)xrow;         // x_0
        unsigned pk = (unsigned)f2bf(v0.x) | ((unsigned)f2bf(v0.y) << 16);
        *(unsigned*)&sh_comb[0][xm][2 * xd] = pk;
        pa = *(const float2*)(xrow + (size_t)1 * kF);   // x_1 (used t=0)
        pb = *(const float2*)(xrow + (size_t)2 * kF);   // x_2 (used t=1)
    }
    __syncthreads();

    // ---- anti-phase offset: half a step (~640cy) for one block of each
    // co-resident pair, so chain A's MFMA phase fills chain B's bubbles.
    if ((bb ^ (bb >> 8)) & 1) __builtin_amdgcn_s_sleep(10);

    // ---- one step; CUR = t&1 compile-time via 2-phase unroll ----
    auto step = [&](int t, int CUR, float2& pf) {
        const short* rowp = &sh_comb[CUR][m16][0];
        bf16x8 bv0 = *(const bf16x8*)(rowp +      q * 8);   // k  0..31
        bf16x8 bv1 = *(const bf16x8*)(rowp + 32 + q * 8);   // k 32..63
        bf16x8 bv2 = *(const bf16x8*)(rowp + 64 + q * 8);   // k 64..95
#pragma unroll
        for (int i = 0; i < 4; ++i) {
            if (i < NT) {                                   // wave-uniform
                f32x4 d;
                d[0] = bias[i][0]; d[1] = bias[i][1];
                d[2] = bias[i][2]; d[3] = bias[i][3];
                d = __builtin_amdgcn_mfma_f32_16x16x32_bf16(wa[i][0], bv0, d, 0, 0, 0);
                d = __builtin_amdgcn_mfma_f32_16x16x32_bf16(wa[i][1], bv1, d, 0, 0, 0);
                d = __builtin_amdgcn_mfma_f32_16x16x32_bf16(wa[i][2], bv2, d, 0, 0, 0);
                if (m16 < kMB)                              // 2 real cols only
                    *(f32x4*)&sh_g[m16][16 * (t0 + i) + 4 * q] = d;
            }
        }
        __syncthreads();                                    // A: sh_g ready

        short* nbuf = &sh_comb[CUR ^ 1][0][0];
        if (pw) {
            f32x4 g = *(const f32x4*)&sh_g[pm][4 * pu];     // i,f,g,o of unit pu
            float i_s = fast_sigmoid(g[0]);
            float f_s = fast_sigmoid(g[1]);
            float g_t = fast_tanh   (g[2]);
            float o_s = fast_sigmoid(g[3]);
            c = fmaf(f_s, c, i_s * g_t);
            lasth = o_s * fast_tanh(c);
            if (t + 1 < kT)
                nbuf[pm * kRowS + kF + pu] = (short)f2bf(lasth);
        } else if (xs) {
            if (t + 1 < kT) {
                unsigned pk = (unsigned)f2bf(pf.x) | ((unsigned)f2bf(pf.y) << 16);
                *(unsigned*)&nbuf[xm * kRowS + 2 * xd] = pk;
            }
            if (t + 3 < kT)                                  // distance-2 prefetch
                pf = *(const float2*)(xrow + (size_t)(t + 3) * kF);
        }
        __syncthreads();                                    // B: panel ready
    };

    for (int t = 0; t < kT; t += 2) {
        step(t,     0, pa);
        step(t + 1, 1, pb);
    }

    // ---- head: relu(h @ W1.T + b1) @ W2.T + b2 + x[b, T-1, 0] ----
    if (pw) sh_hf[pm][pu] = lasth;
    __syncthreads();
    if (tid < kMB * 10) {
        const int m = tid / 10, j = tid % 10;
        float acc = b1[j];
#pragma unroll
        for (int k = 0; k < kH; ++k) acc = fmaf(sh_hf[m][k], W1[j * kH + k], acc);
        sh_head[m][j] = fmaxf(acc, 0.f);
    }
    __syncthreads();
    if (tid < kMB) {
        float acc = b2[0];
#pragma unroll
        for (int j2 = 0; j2 < 10; ++j2) acc = fmaf(sh_head[tid][j2], W2[j2], acc);
        const int bidx = bb * kMB + tid;
        out[bidx] = acc + x[((size_t)bidx * kT + (kT - 1)) * kF];
    }
}

extern "C" void kernel_launch(void* const* d_in, const int* in_sizes, int n_in,
                              void* d_out, int out_size, void* d_ws, size_t ws_size,
                              hipStream_t stream) {
    const float* x    = (const float*)d_in[0];
    const float* W_ih = (const float*)d_in[1];
    const float* W_hh = (const float*)d_in[2];
    const float* b_ih = (const float*)d_in[3];
    const float* b_hh = (const float*)d_in[4];
    const float* W1   = (const float*)d_in[5];
    const float* b1   = (const float*)d_in[6];
    const float* W2   = (const float*)d_in[7];
    const float* b2   = (const float*)d_in[8];
    float* out = (float*)d_out;

    lstm_mfma_offset<<<dim3(1024 / kMB), dim3(256), 0, stream>>>(
        x, W_ih, W_hh, b_ih, b_hh, W1, b1, W2, b2, out);
}